// Round 1
// baseline (81.934 us; speedup 1.0000x reference)
//
#include <hip/hip_runtime.h>
#include <math.h>

#define FEAT 4096       // P*N = 64*64
#define NC   10         // classes
#define ROWS 8          // batch rows per block
#define BLK  256        // threads per block (4 waves)
#define F4   (FEAT/4)   // 1024 float4 per row
#define ITERS (F4/BLK)  // 4 float4 per thread per row

// Kernel A: ew[c][f] = exp(weight[c][f]); lse[c] = log(sum_f ew[c][f])
__global__ __launch_bounds__(BLK) void prep_kernel(const float* __restrict__ weight,
                                                   float* __restrict__ ew,
                                                   float* __restrict__ lse) {
    int c = blockIdx.x;
    int t = threadIdx.x;
    const float4* wv  = (const float4*)(weight + (size_t)c * FEAT);
    float4*       ewv = (float4*)(ew + (size_t)c * FEAT);
    float s = 0.f;
#pragma unroll
    for (int k = 0; k < ITERS; ++k) {
        float4 w4 = wv[k * BLK + t];
        float4 e4;
        e4.x = __expf(w4.x); e4.y = __expf(w4.y);
        e4.z = __expf(w4.z); e4.w = __expf(w4.w);
        ewv[k * BLK + t] = e4;
        s += e4.x + e4.y + e4.z + e4.w;
    }
#pragma unroll
    for (int off = 32; off >= 1; off >>= 1) s += __shfl_xor(s, off, 64);
    __shared__ float ls[BLK / 64];
    if ((t & 63) == 0) ls[t >> 6] = s;
    __syncthreads();
    if (t == 0) lse[c] = __logf(ls[0] + ls[1] + ls[2] + ls[3]);
}

// Kernel B: out[b][c] = log( dot(exp(x[b,:]), ew[c,:]) ) - lse[c]
// PRE=true : wsrc = precomputed exp(weight); lse valid.
// PRE=false: wsrc = raw weight (exp inline); lse computed in-block via sew.
template <bool PRE>
__global__ __launch_bounds__(BLK) void main_kernel(const float* __restrict__ x,
                                                   const float* __restrict__ wsrc,
                                                   const float* __restrict__ lse,
                                                   float* __restrict__ out) {
    const int t  = threadIdx.x;
    const int b0 = blockIdx.x * ROWS;
    const float4* xv = (const float4*)x;
    const float4* wv = (const float4*)wsrc;

    float acc[ROWS][NC];
#pragma unroll
    for (int r = 0; r < ROWS; ++r)
#pragma unroll
        for (int c = 0; c < NC; ++c) acc[r][c] = 0.f;
    float sew[NC];
#pragma unroll
    for (int c = 0; c < NC; ++c) sew[c] = 0.f;

#pragma unroll
    for (int k = 0; k < ITERS; ++k) {
        const int i = k * BLK + t;  // float4 index within a row (coalesced)
        float ex[ROWS][4];
#pragma unroll
        for (int r = 0; r < ROWS; ++r) {
            float4 x4 = xv[(size_t)(b0 + r) * F4 + i];
            ex[r][0] = __expf(x4.x); ex[r][1] = __expf(x4.y);
            ex[r][2] = __expf(x4.z); ex[r][3] = __expf(x4.w);
        }
#pragma unroll
        for (int c = 0; c < NC; ++c) {
            float4 w4 = wv[(size_t)c * F4 + i];
            if (!PRE) {
                w4.x = __expf(w4.x); w4.y = __expf(w4.y);
                w4.z = __expf(w4.z); w4.w = __expf(w4.w);
                sew[c] += (w4.x + w4.y) + (w4.z + w4.w);
            }
#pragma unroll
            for (int r = 0; r < ROWS; ++r) {
                acc[r][c] = fmaf(ex[r][0], w4.x, acc[r][c]);
                acc[r][c] = fmaf(ex[r][1], w4.y, acc[r][c]);
                acc[r][c] = fmaf(ex[r][2], w4.z, acc[r][c]);
                acc[r][c] = fmaf(ex[r][3], w4.w, acc[r][c]);
            }
        }
    }

    // ---- block reduction over 256 threads ----
    __shared__ float red[4][ROWS * NC];
    __shared__ float redw[4][NC];
    const int wave = t >> 6;
    const int lane = t & 63;

#pragma unroll
    for (int r = 0; r < ROWS; ++r)
#pragma unroll
        for (int c = 0; c < NC; ++c) {
            float v = acc[r][c];
#pragma unroll
            for (int off = 32; off >= 1; off >>= 1) v += __shfl_xor(v, off, 64);
            acc[r][c] = v;
        }
    if (!PRE) {
#pragma unroll
        for (int c = 0; c < NC; ++c) {
            float v = sew[c];
#pragma unroll
            for (int off = 32; off >= 1; off >>= 1) v += __shfl_xor(v, off, 64);
            sew[c] = v;
        }
    }
    if (lane == 0) {
#pragma unroll
        for (int r = 0; r < ROWS; ++r)
#pragma unroll
            for (int c = 0; c < NC; ++c) red[wave][r * NC + c] = acc[r][c];
        if (!PRE) {
#pragma unroll
            for (int c = 0; c < NC; ++c) redw[wave][c] = sew[c];
        }
    }
    __syncthreads();
    if (t < ROWS * NC) {
        const int r = t / NC, c = t % NC;
        float v = red[0][t] + red[1][t] + red[2][t] + red[3][t];
        float sub;
        if (PRE) {
            sub = lse[c];
        } else {
            sub = __logf(redw[0][c] + redw[1][c] + redw[2][c] + redw[3][c]);
        }
        out[(size_t)(b0 + r) * NC + c] = __logf(v) - sub;
    }
}

extern "C" void kernel_launch(void* const* d_in, const int* in_sizes, int n_in,
                              void* d_out, int out_size, void* d_ws, size_t ws_size,
                              hipStream_t stream) {
    const float* x      = (const float*)d_in[0];
    const float* weight = (const float*)d_in[1];
    float*       out    = (float*)d_out;

    const int B = in_sizes[0] / FEAT;     // 2048
    const int grid = B / ROWS;            // 256 blocks (B divisible by ROWS)

    const size_t ew_bytes = (size_t)NC * FEAT * sizeof(float);
    const size_t need     = ew_bytes + 256;  // ew table + lse (padded)

    if (ws_size >= need) {
        float* ew  = (float*)d_ws;
        float* lse = (float*)((char*)d_ws + ew_bytes);
        prep_kernel<<<NC, BLK, 0, stream>>>(weight, ew, lse);
        main_kernel<true><<<grid, BLK, 0, stream>>>(x, ew, lse, out);
    } else {
        main_kernel<false><<<grid, BLK, 0, stream>>>(x, weight, nullptr, out);
    }
}

// Round 2
// 80.876 us; speedup vs baseline: 1.0131x; 1.0131x over previous
//
#include <hip/hip_runtime.h>
#include <math.h>

#define FEAT 4096       // P*N = 64*64
#define NC   10         // classes
#define ROWS 2          // batch rows per block (grid = 2048/2 = 1024 -> 4 blocks/CU)
#define BLK  256        // threads per block (4 waves)
#define F4   (FEAT/4)   // 1024 float4 per row
#define ITERS (F4/BLK)  // 4 float4 per thread per row

// Kernel A: ew[c][f] = exp(weight[c][f]); lse[c] = log(sum_f ew[c][f])
__global__ __launch_bounds__(BLK) void prep_kernel(const float* __restrict__ weight,
                                                   float* __restrict__ ew,
                                                   float* __restrict__ lse) {
    int c = blockIdx.x;
    int t = threadIdx.x;
    const float4* wv  = (const float4*)(weight + (size_t)c * FEAT);
    float4*       ewv = (float4*)(ew + (size_t)c * FEAT);
    float s = 0.f;
#pragma unroll
    for (int k = 0; k < ITERS; ++k) {
        float4 w4 = wv[k * BLK + t];
        float4 e4;
        e4.x = __expf(w4.x); e4.y = __expf(w4.y);
        e4.z = __expf(w4.z); e4.w = __expf(w4.w);
        ewv[k * BLK + t] = e4;
        s += e4.x + e4.y + e4.z + e4.w;
    }
#pragma unroll
    for (int off = 32; off >= 1; off >>= 1) s += __shfl_xor(s, off, 64);
    __shared__ float ls[BLK / 64];
    if ((t & 63) == 0) ls[t >> 6] = s;
    __syncthreads();
    if (t == 0) lse[c] = __logf(ls[0] + ls[1] + ls[2] + ls[3]);
}

// Kernel B: out[b][c] = log( dot(exp(x[b,:]), ew[c,:]) ) - lse[c]
// PRE=true : wsrc = precomputed exp(weight); lse valid.
// PRE=false: wsrc = raw weight (exp inline); lse computed in-block via sew.
template <bool PRE>
__global__ __launch_bounds__(BLK) void main_kernel(const float* __restrict__ x,
                                                   const float* __restrict__ wsrc,
                                                   const float* __restrict__ lse,
                                                   float* __restrict__ out) {
    const int t  = threadIdx.x;
    const int b0 = blockIdx.x * ROWS;
    const float4* xv = (const float4*)x;
    const float4* wv = (const float4*)wsrc;

    float acc[ROWS][NC];
#pragma unroll
    for (int r = 0; r < ROWS; ++r)
#pragma unroll
        for (int c = 0; c < NC; ++c) acc[r][c] = 0.f;
    float sew[NC];
#pragma unroll
    for (int c = 0; c < NC; ++c) sew[c] = 0.f;

#pragma unroll
    for (int k = 0; k < ITERS; ++k) {
        const int i = k * BLK + t;  // float4 index within a row (coalesced)
        float ex[ROWS][4];
#pragma unroll
        for (int r = 0; r < ROWS; ++r) {
            float4 x4 = xv[(size_t)(b0 + r) * F4 + i];
            ex[r][0] = __expf(x4.x); ex[r][1] = __expf(x4.y);
            ex[r][2] = __expf(x4.z); ex[r][3] = __expf(x4.w);
        }
#pragma unroll
        for (int c = 0; c < NC; ++c) {
            float4 w4 = wv[(size_t)c * F4 + i];
            if (!PRE) {
                w4.x = __expf(w4.x); w4.y = __expf(w4.y);
                w4.z = __expf(w4.z); w4.w = __expf(w4.w);
                sew[c] += (w4.x + w4.y) + (w4.z + w4.w);
            }
#pragma unroll
            for (int r = 0; r < ROWS; ++r) {
                acc[r][c] = fmaf(ex[r][0], w4.x, acc[r][c]);
                acc[r][c] = fmaf(ex[r][1], w4.y, acc[r][c]);
                acc[r][c] = fmaf(ex[r][2], w4.z, acc[r][c]);
                acc[r][c] = fmaf(ex[r][3], w4.w, acc[r][c]);
            }
        }
    }

    // ---- block reduction over 256 threads ----
    __shared__ float red[4][ROWS * NC];
    __shared__ float redw[4][NC];
    const int wave = t >> 6;
    const int lane = t & 63;

#pragma unroll
    for (int r = 0; r < ROWS; ++r)
#pragma unroll
        for (int c = 0; c < NC; ++c) {
            float v = acc[r][c];
#pragma unroll
            for (int off = 32; off >= 1; off >>= 1) v += __shfl_xor(v, off, 64);
            acc[r][c] = v;
        }
    if (!PRE) {
#pragma unroll
        for (int c = 0; c < NC; ++c) {
            float v = sew[c];
#pragma unroll
            for (int off = 32; off >= 1; off >>= 1) v += __shfl_xor(v, off, 64);
            sew[c] = v;
        }
    }
    if (lane == 0) {
#pragma unroll
        for (int r = 0; r < ROWS; ++r)
#pragma unroll
            for (int c = 0; c < NC; ++c) red[wave][r * NC + c] = acc[r][c];
        if (!PRE) {
#pragma unroll
            for (int c = 0; c < NC; ++c) redw[wave][c] = sew[c];
        }
    }
    __syncthreads();
    if (t < ROWS * NC) {
        const int r = t / NC, c = t % NC;
        float v = red[0][t] + red[1][t] + red[2][t] + red[3][t];
        float sub;
        if (PRE) {
            sub = lse[c];
        } else {
            sub = __logf(redw[0][c] + redw[1][c] + redw[2][c] + redw[3][c]);
        }
        out[(size_t)(b0 + r) * NC + c] = __logf(v) - sub;
    }
}

extern "C" void kernel_launch(void* const* d_in, const int* in_sizes, int n_in,
                              void* d_out, int out_size, void* d_ws, size_t ws_size,
                              hipStream_t stream) {
    const float* x      = (const float*)d_in[0];
    const float* weight = (const float*)d_in[1];
    float*       out    = (float*)d_out;

    const int B = in_sizes[0] / FEAT;     // 2048
    const int grid = B / ROWS;            // 1024 blocks

    const size_t ew_bytes = (size_t)NC * FEAT * sizeof(float);
    const size_t need     = ew_bytes + 256;  // ew table + lse (padded)

    if (ws_size >= need) {
        float* ew  = (float*)d_ws;
        float* lse = (float*)((char*)d_ws + ew_bytes);
        prep_kernel<<<NC, BLK, 0, stream>>>(weight, ew, lse);
        main_kernel<true><<<grid, BLK, 0, stream>>>(x, ew, lse, out);
    } else {
        main_kernel<false><<<grid, BLK, 0, stream>>>(x, weight, nullptr, out);
    }
}